// Round 13
// baseline (3281.528 us; speedup 1.0000x reference)
//
#include <hip/hip_runtime.h>
#include <hip/hip_bf16.h>

typedef __attribute__((ext_vector_type(8))) short short8;
typedef __attribute__((ext_vector_type(4))) short s16x4;
typedef __attribute__((ext_vector_type(4))) float f32x4;
typedef __hip_bfloat16 bf16;

#define AS1 __attribute__((address_space(1)))
#define AS3 __attribute__((address_space(3)))

__device__ __forceinline__ float b2f(short u) {
  union { unsigned int i; float f; } x;
  x.i = ((unsigned int)(unsigned short)u) << 16;
  return x.f;
}
__device__ __forceinline__ short f2bs(float f) {
  bf16 t = __float2bfloat16(f);
  return *reinterpret_cast<short*>(&t);
}

__device__ __forceinline__ void gld_lds16(const void* g, void* lds) {
  __builtin_amdgcn_global_load_lds((const AS1 unsigned int*)g,
                                   (AS3 unsigned int*)lds, 16, 0, 0);
}

// ---------------- weight transpose + fp32->bf16 convert ----------------
__global__ void transpose_conv(const float* __restrict__ src, bf16* __restrict__ dst,
                               int R, int C, int row_off, long long layer_stride) {
  __shared__ float t[32][33];
  int l = blockIdx.z;
  int r0 = blockIdx.y * 32;
  int c0 = blockIdx.x * 32;
  int tx = threadIdx.x & 31, ty = threadIdx.x >> 5;
  const float* s = src + (size_t)l * R * C;
#pragma unroll
  for (int i = 0; i < 4; ++i)
    t[ty + i * 8][tx] = s[(size_t)(r0 + ty + i * 8) * C + c0 + tx];
  __syncthreads();
  bf16* d = dst + (size_t)l * layer_stride;
#pragma unroll
  for (int i = 0; i < 4; ++i) {
    int n = c0 + ty + i * 8, k = r0 + tx;
    d[(size_t)(row_off + n) * R + k] = __float2bfloat16(t[tx][ty + i * 8]);
  }
}

// merged 3-source 768x768 transpose (qkv weight groups); z = l*3 + which
__global__ void transpose_conv3(const float* __restrict__ s0, const float* __restrict__ s1,
                                const float* __restrict__ s2, bf16* __restrict__ dst,
                                long long layer_stride) {
  __shared__ float t[32][33];
  int z = blockIdx.z;
  int which = z % 3, l = z / 3;
  const float* src = (which == 0) ? s0 : (which == 1) ? s1 : s2;
  int r0 = blockIdx.y * 32;
  int c0 = blockIdx.x * 32;
  int tx = threadIdx.x & 31, ty = threadIdx.x >> 5;
  const float* s = src + (size_t)l * 768 * 768;
#pragma unroll
  for (int i = 0; i < 4; ++i)
    t[ty + i * 8][tx] = s[(size_t)(r0 + ty + i * 8) * 768 + c0 + tx];
  __syncthreads();
  bf16* d = dst + (size_t)l * layer_stride;
#pragma unroll
  for (int i = 0; i < 4; ++i) {
    int n = c0 + ty + i * 8, k = r0 + tx;
    d[(size_t)(which * 768 + n) * 768 + k] = __float2bfloat16(t[tx][ty + i * 8]);
  }
}

// dec_w [768][16] fp32 -> dwT [j][k] bf16 (rows 16..127 pre-zeroed)
__global__ void dec_transpose(const float* __restrict__ dw, bf16* __restrict__ dwT) {
  int idx = blockIdx.x * 256 + threadIdx.x;   // 16*768
  if (idx >= 12288) return;
  int k = idx % 768, j = idx / 768;
  dwT[j * 768 + k] = __float2bfloat16(dw[k * 16 + j]);
}

// ---------------- patch embed + pos embed (LDS-staged x patch) ----------------
__global__ __launch_bounds__(256) void patch_embed(const float* __restrict__ x,
                                                   const float* __restrict__ pw,
                                                   const float* __restrict__ pb,
                                                   const float* __restrict__ pos,
                                                   float* __restrict__ xs) {
  __shared__ float xp[16];
  int bn = blockIdx.x;             // [B][N]
  int n = bn & 255, b = bn >> 8;
  int gi = n >> 4, gj = n & 15;
  int tid = threadIdx.x;
  if (tid < 16) {
    int c = tid >> 2, p = (tid >> 1) & 1, q = tid & 1;
    xp[tid] = x[((b * 4 + c) * 32 + gi * 2 + p) * 32 + gj * 2 + q];
  }
  __syncthreads();
  float xv[16];
#pragma unroll
  for (int j = 0; j < 16; ++j) xv[j] = xp[j];
#pragma unroll
  for (int it = 0; it < 3; ++it) {
    int d = tid + it * 256;
    const float* pwr = pw + d * 16;
    float acc = pb[d];
#pragma unroll
    for (int j = 0; j < 16; ++j) acc += xv[j] * pwr[j];
    xs[(size_t)bn * 768 + d] = acc + pos[n * 768 + d];
  }
}

// ---------------- time embedding ----------------
__global__ void temb_kernel(const float* __restrict__ t, float* __restrict__ emb) {
  int b = blockIdx.x;
  int i = threadIdx.x;
  float f = __expf((float)i * (-logf(10000.f) / 127.f));
  float e = t[b] * f;
  emb[b * 256 + i] = sinf(e);
  emb[b * 256 + 128 + i] = cosf(e);
}

// small [32,K]@[K,768] with 8-way k-split + shuffle reduce. MODE 0: fp32+silu, 1: bf16
template <int MODE>
__global__ void smallmm_red(const float* __restrict__ in, const float* __restrict__ w,
                            const float* __restrict__ bias, void* __restrict__ out, int K) {
  int tid = threadIdx.x;
  int s = tid & 7, o = blockIdx.x * 32 + (tid >> 3);
  int d = o % 768, b = o / 768;
  int Ks = K >> 3, k0 = s * Ks;
  const float* ir = in + b * K + k0;
  const float* wr = w + (size_t)k0 * 768 + d;
  float a = 0.f;
  for (int i = 0; i < Ks; ++i) a += ir[i] * wr[(size_t)i * 768];
  a += __shfl_xor(a, 1);
  a += __shfl_xor(a, 2);
  a += __shfl_xor(a, 4);
  if (s == 0) {
    a += bias[d];
    if (MODE == 0) {
      a = a / (1.f + __expf(-a));
      ((float*)out)[o] = a;
    } else {
      ((bf16*)out)[o] = __float2bfloat16(a);
    }
  }
}

// bias table in MFMA D-fragment order, pre-scaled by 8
__global__ void build_btab_frag(const float* __restrict__ rpb, bf16* __restrict__ btf) {
  int idx = blockIdx.x * 256 + threadIdx.x;    // 12*12*65536
  int t = idx & 65535;
  int lh = idx >> 16;
  int h = lh % 12, l = lh / 12;
  int r = t & 3; t >>= 2;
  int lane = t & 63; t >>= 6;
  int i = t & 3; t >>= 2;
  int w = t & 3; t >>= 2;
  int jb = t & 1; t >>= 1;
  int hc = t & 7;
  int q = w * 64 + i * 16 + (lane & 15);
  int k = hc * 32 + jb * 16 + (lane >> 4) * 4 + r;
  int ih = (q >> 4) - (k >> 4) + 15;
  int iw = (q & 15) - (k & 15) + 15;
  btf[idx] = __float2bfloat16(8.0f * rpb[((l * 31 + ih) * 31 + iw) * 12 + h]);
}

// ---------------- LayerNorm fp32 -> bf16, wave-per-row (no LDS, no sync) ----------
__global__ __launch_bounds__(256) void ln_bf16_kernel(const float* __restrict__ x,
                                                      const float* __restrict__ w,
                                                      const float* __restrict__ b,
                                                      bf16* __restrict__ out) {
  int row = blockIdx.x * 4 + (threadIdx.x >> 6);
  int lane = threadIdx.x & 63;
  const float* xr = x + (size_t)row * 768;
  float v[12];
  float s = 0.f, s2 = 0.f;
#pragma unroll
  for (int k = 0; k < 12; ++k) {
    v[k] = xr[lane + k * 64];
    s += v[k];
    s2 += v[k] * v[k];
  }
#pragma unroll
  for (int off = 32; off; off >>= 1) {
    s += __shfl_xor(s, off);
    s2 += __shfl_xor(s2, off);
  }
  float m = s * (1.f / 768.f);
  float var = s2 * (1.f / 768.f) - m * m;
  float r = rsqrtf(var + 1e-6f);
  bf16* orow = out + (size_t)row * 768;
#pragma unroll
  for (int k = 0; k < 12; ++k) {
    int c = lane + k * 64;
    orow[c] = __float2bfloat16((v[k] - m) * r * w[c] + b[c]);
  }
}

// ---------------- MFMA GEMM 128x128, BK=64, dbuf, swizzled LDS, VECTORIZED EPI ----
// K-loop identical to R4/R11 (proven ~0 conflicts). Epilogue: acc staged to LDS with
// ((row&7)<<4) byte XOR, then coalesced 16B/lane global IO.
// EPI 0: qkv bf16 (+bias+ttok, ldc=2304); 1: fp32 +bias+resid; 2: bf16 silu(+bias)
// EPI 3: ttok producer (rows<32);         4: decode/unpatchify (col<16)  [scalar]
template <int EPI>
__global__ __launch_bounds__(256) void gemm128(
    const bf16* __restrict__ A, int lda, const bf16* __restrict__ BT, int ldb, int K,
    const float* __restrict__ p0, const float* __restrict__ p1,
    const float* __restrict__ p2, const float* __restrict__ p3,
    const float* __restrict__ p4, const float* __restrict__ p5,
    const float* __restrict__ resid, float* __restrict__ outF,
    bf16* __restrict__ outB, int ldc) {
  __shared__ __align__(16) char lds[65536];
  const int tid = threadIdx.x;
  const int wid = tid >> 6, lane = tid & 63;
  const int wr = wid >> 1, wc = wid & 1;
  const int nwg = gridDim.x * gridDim.y;
  const int bid = blockIdx.y * gridDim.x + blockIdx.x;
  const int swzb = (bid & 7) * (nwg >> 3) + (bid >> 3);   // all grids %8==0
  const int m0 = (swzb / gridDim.x) * 128, n0 = (swzb % gridDim.x) * 128;
  const int l16 = lane & 15, lq = lane >> 4;

  f32x4 acc[4][4];
#pragma unroll
  for (int i = 0; i < 4; ++i)
#pragma unroll
    for (int j = 0; j < 4; ++j) acc[i][j] = f32x4{0.f, 0.f, 0.f, 0.f};

  const int arow = tid >> 3;
  const int aslot = (tid & 7) ^ (arow & 7);
  const bf16* gA = A + (size_t)(m0 + arow) * lda + aslot * 8;
  const bf16* gB = BT + (size_t)(n0 + arow) * ldb + aslot * 8;
  const unsigned offw = (unsigned)__builtin_amdgcn_readfirstlane((tid & ~63) * 16);

  const int NT = K >> 6;
  auto stage = [&](int buf, int t) {
    char* p = lds + buf * 32768;
    const int k = t * 64;
#pragma unroll
    for (int it = 0; it < 4; ++it) {
      gld_lds16(gA + (size_t)it * 32 * lda + k, p + it * 4096 + offw);
      gld_lds16(gB + (size_t)it * 32 * ldb + k, p + 16384 + it * 4096 + offw);
    }
  };

  stage(0, 0);
  const unsigned swb = ((unsigned)(l16 & 7)) << 4;
  for (int t = 0; t < NT; ++t) {
    char* cur = lds + (t & 1) * 32768;
    if (t + 1 < NT) {
      stage((t + 1) & 1, t + 1);
      asm volatile("s_waitcnt vmcnt(8)" ::: "memory");
    } else {
      asm volatile("s_waitcnt vmcnt(0)" ::: "memory");
    }
    __builtin_amdgcn_s_barrier();
#pragma unroll
    for (int ks = 0; ks < 2; ++ks) {
      short8 af[4], bfr[4];
      const unsigned ko = ((unsigned)(ks * 64 + lq * 16)) ^ swb;
#pragma unroll
      for (int i = 0; i < 4; ++i) {
        af[i]  = *(const short8*)(cur + (wr * 64 + i * 16 + l16) * 128 + ko);
        bfr[i] = *(const short8*)(cur + 16384 + (wc * 64 + i * 16 + l16) * 128 + ko);
      }
#pragma unroll
      for (int i = 0; i < 4; ++i)
#pragma unroll
        for (int j = 0; j < 4; ++j)
          acc[i][j] = __builtin_amdgcn_mfma_f32_16x16x32_bf16(af[i], bfr[j], acc[i][j], 0, 0, 0);
    }
    __builtin_amdgcn_s_barrier();
  }
  // all waves past final barrier -> LDS reusable for epilogue

  if constexpr (EPI == 0 || EPI == 2) {
    // bf16 out: stage [128 rows][256B] swizzled, then 16B/lane coalesced stores
    int s = 0;
    const float *bs = p0, *ts = nullptr;
    if constexpr (EPI == 0) {
      s = n0 / 768;
      bs = (s == 0) ? p0 : (s == 1) ? p1 : p2;
      ts = (s == 0) ? p3 : (s == 1) ? p4 : p5;
    }
    const int d0 = n0 - s * 768;
#pragma unroll
    for (int i = 0; i < 4; ++i)
#pragma unroll
      for (int j = 0; j < 4; ++j)
#pragma unroll
        for (int r = 0; r < 4; ++r) {
          int lr = wr * 64 + i * 16 + lq * 4 + r;
          int lc = wc * 64 + j * 16 + l16;
          float v = acc[i][j][r];
          if constexpr (EPI == 0) {
            int d = d0 + lc;
            int b = (m0 + lr) >> 8;
            v += bs[d] + ts[b * 768 + d];
          } else {
            v += p0[n0 + lc];
            v = v / (1.f + __expf(-v));
          }
          unsigned byte = (unsigned)lr * 256 + (((unsigned)(lc * 2)) ^ (((unsigned)lr & 7) << 4));
          *(short*)(lds + byte) = f2bs(v);
        }
    __syncthreads();
    int rrow = tid >> 1, h = tid & 1;
    bf16* orow = outB + (size_t)(m0 + rrow) * ldc + n0 + h * 64;
#pragma unroll
    for (int c = 0; c < 8; ++c) {
      unsigned byte = (unsigned)rrow * 256 +
                      (((unsigned)(h * 128 + c * 16)) ^ (((unsigned)rrow & 7) << 4));
      *(short8*)(orow + c * 8) = *(const short8*)(lds + byte);
    }
  } else if constexpr (EPI == 1) {
    // fp32 out + resid: stage fp32 [128][512B] swizzled; vectorized resid/bias add
#pragma unroll
    for (int i = 0; i < 4; ++i)
#pragma unroll
      for (int j = 0; j < 4; ++j)
#pragma unroll
        for (int r = 0; r < 4; ++r) {
          int lr = wr * 64 + i * 16 + lq * 4 + r;
          int lc = wc * 64 + j * 16 + l16;
          unsigned byte = (unsigned)lr * 512 + (((unsigned)(lc * 4)) ^ (((unsigned)lr & 7) << 4));
          *(float*)(lds + byte) = acc[i][j][r];
        }
    __syncthreads();
    int rrow = tid >> 2, qq = tid & 3;
#pragma unroll
    for (int p = 0; p < 2; ++p) {
      int lr = p * 64 + rrow;
      const float* rres = resid + (size_t)(m0 + lr) * ldc + n0 + qq * 32;
      float* ro = outF + (size_t)(m0 + lr) * ldc + n0 + qq * 32;
      const float* bb = p0 + n0 + qq * 32;
#pragma unroll
      for (int c = 0; c < 8; ++c) {
        unsigned byte = (unsigned)lr * 512 +
                        (((unsigned)(qq * 128 + c * 16)) ^ (((unsigned)lr & 7) << 4));
        f32x4 v = *(const f32x4*)(lds + byte);
        f32x4 rs = *(const f32x4*)(rres + c * 4);
        f32x4 bv = *(const f32x4*)(bb + c * 4);
        v = v + rs + bv;
        *(f32x4*)(ro + c * 4) = v;
      }
    }
  } else {
    // scalar epilogue for ttok (EPI3) / decode (EPI4)
#pragma unroll
    for (int i = 0; i < 4; ++i) {
#pragma unroll
      for (int j = 0; j < 4; ++j) {
#pragma unroll
        for (int r = 0; r < 4; ++r) {
          int row = m0 + wr * 64 + i * 16 + lq * 4 + r;
          int col = n0 + wc * 64 + j * 16 + l16;
          float v = acc[i][j][r];
          if constexpr (EPI == 3) {
            if (row < 32) {
              int l = col / 2304;
              int r2c = col - l * 2304;
              int s = r2c / 768, d = r2c - s * 768;
              const float* bsp = (s == 0) ? p0 : (s == 1) ? p1 : p2;
              v += bsp[l * 768 + d];
              outF[(size_t)((l * 3 + s) * 32 + row) * 768 + d] = v;
            }
          } else {
            if (col < 16) {
              v += p0[col];
              int b = row >> 8, n = row & 255;
              int gi = n >> 4, gj = n & 15;
              int c = col >> 2, pp = (col >> 1) & 1, qq2 = col & 1;
              outF[((b * 4 + c) * 32 + gi * 2 + pp) * 32 + gj * 2 + qq2] = v;
            }
          }
        }
      }
    }
  }
}

// ---------------- MFMA attention v3: transposed-S, single P buffer, setprio -------
__global__ __launch_bounds__(256) void attn_mfma(const bf16* __restrict__ qkv,
                                                 const bf16* __restrict__ btf,
                                                 bf16* __restrict__ obuf) {
  __shared__ __align__(16) char lds[49152];
  const int tid = threadIdx.x;
  const int wave = tid >> 6, lane = tid & 63;
  const int l16 = lane & 15, lq = lane >> 4;
  const int b = blockIdx.x / 12, h = blockIdx.x % 12;
  const bf16* qb = qkv + (size_t)b * 256 * 2304;

  {
    const short8* vrow = (const short8*)(qb + (size_t)tid * 2304 + 1536 + h * 64);
    short8 vv[8];
#pragma unroll
    for (int c = 0; c < 8; ++c) vv[c] = vrow[c];
#pragma unroll
    for (int c = 0; c < 8; ++c)
#pragma unroll
      for (int e = 0; e < 8; ++e) {
        int d = c * 8 + e;
        unsigned off = (unsigned)(d * 512 + tid * 2) ^ ((unsigned)(d & 7) << 4);
        *(short*)(lds + off) = vv[c][e];
      }
  }
  short8 qf[4][2];
#pragma unroll
  for (int i = 0; i < 4; ++i)
#pragma unroll
    for (int ks = 0; ks < 2; ++ks)
      qf[i][ks] = *(const short8*)(qb + (size_t)(wave * 64 + i * 16 + l16) * 2304 +
                                   h * 64 + ks * 32 + lq * 8);
  __syncthreads();

  f32x4 oacc[4][4];
#pragma unroll
  for (int i = 0; i < 4; ++i)
#pragma unroll
    for (int j = 0; j < 4; ++j) oacc[i][j] = f32x4{0.f, 0.f, 0.f, 0.f};
  float lp[4] = {0.f, 0.f, 0.f, 0.f};
  const bf16* bl = btf + (size_t)h * 65536 + lane * 4;
  const unsigned swzv = ((unsigned)(l16 & 7)) << 4;
  const unsigned swzp = ((unsigned)(l16 & 3)) << 4;
  char* Pw = lds + 32768 + wave * 4096;

  for (int hc = 0; hc < 8; ++hc) {
    short8 kf[2][2];
#pragma unroll
    for (int jb = 0; jb < 2; ++jb) {
      const bf16* kr = qb + (size_t)(hc * 32 + jb * 16 + l16) * 2304 + 768 + h * 64 + lq * 8;
      kf[jb][0] = *(const short8*)(kr);
      kf[jb][1] = *(const short8*)(kr + 32);
    }
    f32x4 sacc[4][2];
#pragma unroll
    for (int i = 0; i < 4; ++i)
#pragma unroll
      for (int jb = 0; jb < 2; ++jb) {
        s16x4 bv = *(const s16x4*)(bl + ((size_t)((hc * 2 + jb) * 16 + wave * 4 + i) << 8));
        sacc[i][jb] = f32x4{b2f(bv[0]), b2f(bv[1]), b2f(bv[2]), b2f(bv[3])};
      }
    __builtin_amdgcn_s_setprio(1);
#pragma unroll
    for (int jb = 0; jb < 2; ++jb)
#pragma unroll
      for (int i = 0; i < 4; ++i) {
        sacc[i][jb] = __builtin_amdgcn_mfma_f32_16x16x32_bf16(kf[jb][0], qf[i][0], sacc[i][jb], 0, 0, 0);
        sacc[i][jb] = __builtin_amdgcn_mfma_f32_16x16x32_bf16(kf[jb][1], qf[i][1], sacc[i][jb], 0, 0, 0);
      }
    __builtin_amdgcn_s_setprio(0);
#pragma unroll
    for (int i = 0; i < 4; ++i)
#pragma unroll
      for (int jb = 0; jb < 2; ++jb) {
        float p0 = __expf(sacc[i][jb][0] * 0.125f);
        float p1 = __expf(sacc[i][jb][1] * 0.125f);
        float p2 = __expf(sacc[i][jb][2] * 0.125f);
        float p3 = __expf(sacc[i][jb][3] * 0.125f);
        lp[i] += (p0 + p1) + (p2 + p3);
        s16x4 pk = {f2bs(p0), f2bs(p1), f2bs(p2), f2bs(p3)};
        *(s16x4*)(Pw + (i * 16 + l16) * 64 + (((unsigned)(jb * 32 + lq * 8)) ^ swzp)) = pk;
      }
    asm volatile("s_waitcnt lgkmcnt(0)" ::: "memory");
    __builtin_amdgcn_sched_barrier(0);
    short8 pa[4], vb[4];
#pragma unroll
    for (int i = 0; i < 4; ++i)
      pa[i] = *(const short8*)(Pw + (i * 16 + l16) * 64 + (((unsigned)(lq * 16)) ^ swzp));
#pragma unroll
    for (int dj = 0; dj < 4; ++dj)
      vb[dj] = *(const short8*)(lds + (dj * 16 + l16) * 512 +
                                (((unsigned)(hc * 64 + lq * 16)) ^ swzv));
    __builtin_amdgcn_s_setprio(1);
#pragma unroll
    for (int i = 0; i < 4; ++i)
#pragma unroll
      for (int dj = 0; dj < 4; ++dj)
        oacc[i][dj] = __builtin_amdgcn_mfma_f32_16x16x32_bf16(pa[i], vb[dj], oacc[i][dj], 0, 0, 0);
    __builtin_amdgcn_s_setprio(0);
  }

#pragma unroll
  for (int i = 0; i < 4; ++i) {
    float l = lp[i];
    l += __shfl_xor(l, 16);
    l += __shfl_xor(l, 32);
#pragma unroll
    for (int r = 0; r < 4; ++r) {
      float linv = 1.f / __shfl(l, lq * 4 + r);
      int grow = b * 256 + wave * 64 + i * 16 + lq * 4 + r;
#pragma unroll
      for (int dj = 0; dj < 4; ++dj)
        obuf[(size_t)grow * 768 + h * 64 + dj * 16 + l16] =
            __float2bfloat16(oacc[i][dj][r] * linv);
    }
  }
}

extern "C" void kernel_launch(void* const* d_in, const int* in_sizes, int n_in,
                              void* d_out, int out_size, void* d_ws, size_t ws_size,
                              hipStream_t stream) {
  (void)in_sizes; (void)n_in; (void)out_size; (void)ws_size;
  const float* x       = (const float*)d_in[0];
  const float* t_in    = (const float*)d_in[1];
  const float* patch_w = (const float*)d_in[2];
  const float* patch_b = (const float*)d_in[3];
  const float* pos     = (const float*)d_in[4];
  const float* t_w1    = (const float*)d_in[5];
  const float* t_b1    = (const float*)d_in[6];
  const float* t_w2    = (const float*)d_in[7];
  const float* t_b2    = (const float*)d_in[8];
  const float* norm1_w = (const float*)d_in[9];
  const float* norm1_b = (const float*)d_in[10];
  const float* wqs     = (const float*)d_in[11];
  const float* bqs     = (const float*)d_in[12];
  const float* wqt     = (const float*)d_in[13];
  const float* bqt     = (const float*)d_in[14];
  const float* wks     = (const float*)d_in[15];
  const float* bks     = (const float*)d_in[16];
  const float* wkt     = (const float*)d_in[17];
  const float* bkt     = (const float*)d_in[18];
  const float* wvs     = (const float*)d_in[19];
  const float* bvs     = (const float*)d_in[20];
  const float* wvt     = (const float*)d_in[21];
  const float* bvt     = (const float*)d_in[22];
  const float* projw   = (const float*)d_in[23];
  const float* projb   = (const float*)d_in[24];
  const float* rpb     = (const float*)d_in[25];
  const float* norm2_w = (const float*)d_in[26];
  const float* norm2_b = (const float*)d_in[27];
  const float* mlp_w1  = (const float*)d_in[28];
  const float* mlp_b1  = (const float*)d_in[29];
  const float* mlp_w2  = (const float*)d_in[30];
  const float* mlp_b2  = (const float*)d_in[31];
  const float* norm_w  = (const float*)d_in[32];
  const float* norm_b  = (const float*)d_in[33];
  const float* dec_w   = (const float*)d_in[34];
  const float* dec_b   = (const float*)d_in[35];

  char* ws = (char*)d_ws;
  size_t off = 0;
  auto alloc = [&](size_t bytes) -> void* {
    void* p = ws + off;
    off += (bytes + 255) & ~(size_t)255;
    return p;
  };
  bf16* wqkvT = (bf16*)alloc(12ull * 2304 * 768 * 2);
  bf16* projT = (bf16*)alloc(12ull * 768 * 768 * 2);
  bf16* mlp1T = (bf16*)alloc(12ull * 3072 * 768 * 2);
  bf16* mlp2T = (bf16*)alloc(12ull * 768 * 3072 * 2);
  bf16* wtT   = (bf16*)alloc(12ull * 2304 * 768 * 2);
  float* xs   = (float*)alloc(8192ull * 768 * 4);
  bf16* hbuf  = (bf16*)alloc(8192ull * 768 * 2);
  bf16* qkvb  = (bf16*)alloc(8192ull * 2304 * 2);
  bf16* obuf  = (bf16*)alloc(8192ull * 768 * 2);
  bf16* btabf = (bf16*)alloc(12ull * 12 * 256 * 256 * 2);
  float* ttok = (float*)alloc(12ull * 3 * 32 * 768 * 4);
  bf16* xtb   = (bf16*)alloc(128ull * 768 * 2);
  bf16* dwT   = (bf16*)alloc(128ull * 768 * 2);
  float* emb  = (float*)alloc(32ull * 256 * 4);
  float* h1   = (float*)alloc(32ull * 768 * 4);
  bf16* hmlp  = qkvb;   // 8192*3072*2 fits in qkvb+obuf, both dead by mlp1

  hipMemsetAsync(xtb, 0, 128ull * 768 * 2, stream);
  hipMemsetAsync(dwT, 0, 128ull * 768 * 2, stream);

  transpose_conv3<<<dim3(24, 24, 36), 256, 0, stream>>>(wqs, wks, wvs, wqkvT, 2304ll * 768);
  transpose_conv3<<<dim3(24, 24, 36), 256, 0, stream>>>(wqt, wkt, wvt, wtT, 2304ll * 768);
  transpose_conv<<<dim3(24, 24, 12), 256, 0, stream>>>(projw, projT, 768, 768, 0, 768ll * 768);
  transpose_conv<<<dim3(96, 24, 12), 256, 0, stream>>>(mlp_w1, mlp1T, 768, 3072, 0, 3072ll * 768);
  transpose_conv<<<dim3(24, 96, 12), 256, 0, stream>>>(mlp_w2, mlp2T, 3072, 768, 0, 768ll * 3072);
  dec_transpose<<<48, 256, 0, stream>>>(dec_w, dwT);
  build_btab_frag<<<36864, 256, 0, stream>>>(rpb, btabf);

  temb_kernel<<<32, 128, 0, stream>>>(t_in, emb);
  smallmm_red<0><<<768, 256, 0, stream>>>(emb, t_w1, t_b1, h1, 256);
  smallmm_red<1><<<768, 256, 0, stream>>>(h1, t_w2, t_b2, xtb, 768);
  gemm128<3><<<dim3(216, 1), 256, 0, stream>>>(
      xtb, 768, wtT, 768, 768, bqt, bkt, bvt, nullptr, nullptr, nullptr,
      nullptr, ttok, nullptr, 0);

  patch_embed<<<8192, 256, 0, stream>>>(x, patch_w, patch_b, pos, xs);

  for (int l = 0; l < 12; ++l) {
    ln_bf16_kernel<<<2048, 256, 0, stream>>>(xs, norm1_w + l * 768, norm1_b + l * 768, hbuf);
    gemm128<0><<<dim3(18, 64), 256, 0, stream>>>(
        hbuf, 768, wqkvT + (size_t)l * 2304 * 768, 768, 768,
        bqs + l * 768, bks + l * 768, bvs + l * 768,
        ttok + (size_t)(l * 3 + 0) * 32 * 768,
        ttok + (size_t)(l * 3 + 1) * 32 * 768,
        ttok + (size_t)(l * 3 + 2) * 32 * 768,
        nullptr, nullptr, qkvb, 2304);
    attn_mfma<<<384, 256, 0, stream>>>(qkvb, btabf + (size_t)l * 12 * 65536, obuf);
    gemm128<1><<<dim3(6, 64), 256, 0, stream>>>(
        obuf, 768, projT + (size_t)l * 768 * 768, 768, 768,
        projb + l * 768, nullptr, nullptr, nullptr, nullptr, nullptr,
        xs, xs, nullptr, 768);
    ln_bf16_kernel<<<2048, 256, 0, stream>>>(xs, norm2_w + l * 768, norm2_b + l * 768, hbuf);
    gemm128<2><<<dim3(24, 64), 256, 0, stream>>>(
        hbuf, 768, mlp1T + (size_t)l * 3072 * 768, 768, 768,
        mlp_b1 + l * 3072, nullptr, nullptr, nullptr, nullptr, nullptr,
        nullptr, nullptr, hmlp, 3072);
    gemm128<1><<<dim3(6, 64), 256, 0, stream>>>(
        hmlp, 3072, mlp2T + (size_t)l * 768 * 3072, 3072, 3072,
        mlp_b2 + l * 768, nullptr, nullptr, nullptr, nullptr, nullptr,
        xs, xs, nullptr, 768);
  }
  ln_bf16_kernel<<<2048, 256, 0, stream>>>(xs, norm_w, norm_b, hbuf);
  gemm128<4><<<dim3(1, 64), 256, 0, stream>>>(
      hbuf, 768, dwT, 768, 768, dec_b, nullptr, nullptr, nullptr, nullptr, nullptr,
      nullptr, (float*)d_out, nullptr, 0);
}

// Round 14
// 2724.766 us; speedup vs baseline: 1.2043x; 1.2043x over previous
//
#include <hip/hip_runtime.h>
#include <hip/hip_bf16.h>

typedef __attribute__((ext_vector_type(8))) short short8;
typedef __attribute__((ext_vector_type(4))) short s16x4;
typedef __attribute__((ext_vector_type(4))) float f32x4;
typedef __hip_bfloat16 bf16;

#define AS1 __attribute__((address_space(1)))
#define AS3 __attribute__((address_space(3)))

__device__ __forceinline__ float b2f(short u) {
  union { unsigned int i; float f; } x;
  x.i = ((unsigned int)(unsigned short)u) << 16;
  return x.f;
}
__device__ __forceinline__ short f2bs(float f) {
  bf16 t = __float2bfloat16(f);
  return *reinterpret_cast<short*>(&t);
}

__device__ __forceinline__ void gld_lds16(const void* g, void* lds) {
  __builtin_amdgcn_global_load_lds((const AS1 unsigned int*)g,
                                   (AS3 unsigned int*)lds, 16, 0, 0);
}

// ---------------- weight transpose + fp32->bf16 convert ----------------
__global__ void transpose_conv(const float* __restrict__ src, bf16* __restrict__ dst,
                               int R, int C, int row_off, long long layer_stride) {
  __shared__ float t[32][33];
  int l = blockIdx.z;
  int r0 = blockIdx.y * 32;
  int c0 = blockIdx.x * 32;
  int tx = threadIdx.x & 31, ty = threadIdx.x >> 5;
  const float* s = src + (size_t)l * R * C;
#pragma unroll
  for (int i = 0; i < 4; ++i)
    t[ty + i * 8][tx] = s[(size_t)(r0 + ty + i * 8) * C + c0 + tx];
  __syncthreads();
  bf16* d = dst + (size_t)l * layer_stride;
#pragma unroll
  for (int i = 0; i < 4; ++i) {
    int n = c0 + ty + i * 8, k = r0 + tx;
    d[(size_t)(row_off + n) * R + k] = __float2bfloat16(t[tx][ty + i * 8]);
  }
}

// merged 3-source 768x768 transpose (qkv weight groups); z = l*3 + which
__global__ void transpose_conv3(const float* __restrict__ s0, const float* __restrict__ s1,
                                const float* __restrict__ s2, bf16* __restrict__ dst,
                                long long layer_stride) {
  __shared__ float t[32][33];
  int z = blockIdx.z;
  int which = z % 3, l = z / 3;
  const float* src = (which == 0) ? s0 : (which == 1) ? s1 : s2;
  int r0 = blockIdx.y * 32;
  int c0 = blockIdx.x * 32;
  int tx = threadIdx.x & 31, ty = threadIdx.x >> 5;
  const float* s = src + (size_t)l * 768 * 768;
#pragma unroll
  for (int i = 0; i < 4; ++i)
    t[ty + i * 8][tx] = s[(size_t)(r0 + ty + i * 8) * 768 + c0 + tx];
  __syncthreads();
  bf16* d = dst + (size_t)l * layer_stride;
#pragma unroll
  for (int i = 0; i < 4; ++i) {
    int n = c0 + ty + i * 8, k = r0 + tx;
    d[(size_t)(which * 768 + n) * 768 + k] = __float2bfloat16(t[tx][ty + i * 8]);
  }
}

// dec_w [768][16] fp32 -> dwT [j][k] bf16 (rows 16..127 pre-zeroed)
__global__ void dec_transpose(const float* __restrict__ dw, bf16* __restrict__ dwT) {
  int idx = blockIdx.x * 256 + threadIdx.x;   // 16*768
  if (idx >= 12288) return;
  int k = idx % 768, j = idx / 768;
  dwT[j * 768 + k] = __float2bfloat16(dw[k * 16 + j]);
}

// ---------------- patch embed + pos embed (LDS-staged x patch) ----------------
__global__ __launch_bounds__(256) void patch_embed(const float* __restrict__ x,
                                                   const float* __restrict__ pw,
                                                   const float* __restrict__ pb,
                                                   const float* __restrict__ pos,
                                                   float* __restrict__ xs) {
  __shared__ float xp[16];
  int bn = blockIdx.x;             // [B][N]
  int n = bn & 255, b = bn >> 8;
  int gi = n >> 4, gj = n & 15;
  int tid = threadIdx.x;
  if (tid < 16) {
    int c = tid >> 2, p = (tid >> 1) & 1, q = tid & 1;
    xp[tid] = x[((b * 4 + c) * 32 + gi * 2 + p) * 32 + gj * 2 + q];
  }
  __syncthreads();
  float xv[16];
#pragma unroll
  for (int j = 0; j < 16; ++j) xv[j] = xp[j];
#pragma unroll
  for (int it = 0; it < 3; ++it) {
    int d = tid + it * 256;
    const float* pwr = pw + d * 16;
    float acc = pb[d];
#pragma unroll
    for (int j = 0; j < 16; ++j) acc += xv[j] * pwr[j];
    xs[(size_t)bn * 768 + d] = acc + pos[n * 768 + d];
  }
}

// ---------------- time embedding ----------------
__global__ void temb_kernel(const float* __restrict__ t, float* __restrict__ emb) {
  int b = blockIdx.x;
  int i = threadIdx.x;
  float f = __expf((float)i * (-logf(10000.f) / 127.f));
  float e = t[b] * f;
  emb[b * 256 + i] = sinf(e);
  emb[b * 256 + 128 + i] = cosf(e);
}

// small [32,K]@[K,768] with 8-way k-split + shuffle reduce. MODE 0: fp32+silu, 1: bf16
template <int MODE>
__global__ void smallmm_red(const float* __restrict__ in, const float* __restrict__ w,
                            const float* __restrict__ bias, void* __restrict__ out, int K) {
  int tid = threadIdx.x;
  int s = tid & 7, o = blockIdx.x * 32 + (tid >> 3);
  int d = o % 768, b = o / 768;
  int Ks = K >> 3, k0 = s * Ks;
  const float* ir = in + b * K + k0;
  const float* wr = w + (size_t)k0 * 768 + d;
  float a = 0.f;
  for (int i = 0; i < Ks; ++i) a += ir[i] * wr[(size_t)i * 768];
  a += __shfl_xor(a, 1);
  a += __shfl_xor(a, 2);
  a += __shfl_xor(a, 4);
  if (s == 0) {
    a += bias[d];
    if (MODE == 0) {
      a = a / (1.f + __expf(-a));
      ((float*)out)[o] = a;
    } else {
      ((bf16*)out)[o] = __float2bfloat16(a);
    }
  }
}

// bias table in MFMA D-fragment order, pre-scaled by 8
__global__ void build_btab_frag(const float* __restrict__ rpb, bf16* __restrict__ btf) {
  int idx = blockIdx.x * 256 + threadIdx.x;    // 12*12*65536
  int t = idx & 65535;
  int lh = idx >> 16;
  int h = lh % 12, l = lh / 12;
  int r = t & 3; t >>= 2;
  int lane = t & 63; t >>= 6;
  int i = t & 3; t >>= 2;
  int w = t & 3; t >>= 2;
  int jb = t & 1; t >>= 1;
  int hc = t & 7;
  int q = w * 64 + i * 16 + (lane & 15);
  int k = hc * 32 + jb * 16 + (lane >> 4) * 4 + r;
  int ih = (q >> 4) - (k >> 4) + 15;
  int iw = (q & 15) - (k & 15) + 15;
  btf[idx] = __float2bfloat16(8.0f * rpb[((l * 31 + ih) * 31 + iw) * 12 + h]);
}

// ---------------- LayerNorm fp32 -> bf16, wave-per-row (no LDS, no sync) ----------
__global__ __launch_bounds__(256) void ln_bf16_kernel(const float* __restrict__ x,
                                                      const float* __restrict__ w,
                                                      const float* __restrict__ b,
                                                      bf16* __restrict__ out) {
  int row = blockIdx.x * 4 + (threadIdx.x >> 6);
  int lane = threadIdx.x & 63;
  const float* xr = x + (size_t)row * 768;
  float v[12];
  float s = 0.f, s2 = 0.f;
#pragma unroll
  for (int k = 0; k < 12; ++k) {
    v[k] = xr[lane + k * 64];
    s += v[k];
    s2 += v[k] * v[k];
  }
#pragma unroll
  for (int off = 32; off; off >>= 1) {
    s += __shfl_xor(s, off);
    s2 += __shfl_xor(s2, off);
  }
  float m = s * (1.f / 768.f);
  float var = s2 * (1.f / 768.f) - m * m;
  float r = rsqrtf(var + 1e-6f);
  bf16* orow = out + (size_t)row * 768;
#pragma unroll
  for (int k = 0; k < 12; ++k) {
    int c = lane + k * 64;
    orow[c] = __float2bfloat16((v[k] - m) * r * w[c] + b[c]);
  }
}

// ---------------- MFMA GEMM 128x128, BK=64, dbuf 2-phase, swizzled LDS (R12) ------
// LDS 64KB (A 2x16KB @0, B 2x16KB @32768) -> 2 blocks/CU. ZERO measured conflicts.
// Scalar epilogue (stores are HW-coalesced; LDS-roundtrip epilogue measured SLOWER, R13).
// EPI 0: qkv bf16 (+bias+ttok, ldc=2304); 1: fp32 +bias+resid; 2: bf16 silu(+bias)
// EPI 3: ttok producer (rows<32);         4: decode/unpatchify (col<16)
template <int EPI>
__global__ __launch_bounds__(256) void gemm128(
    const bf16* __restrict__ A, int lda, const bf16* __restrict__ BT, int ldb, int K,
    const float* __restrict__ p0, const float* __restrict__ p1,
    const float* __restrict__ p2, const float* __restrict__ p3,
    const float* __restrict__ p4, const float* __restrict__ p5,
    const float* __restrict__ resid, float* __restrict__ outF,
    bf16* __restrict__ outB, int ldc) {
  __shared__ __align__(16) char lds[65536];
  const int tid = threadIdx.x;
  const int wid = tid >> 6, lane = tid & 63;
  const int wr = wid >> 1, wc = wid & 1;
  const int nwg = gridDim.x * gridDim.y;
  const int bid = blockIdx.y * gridDim.x + blockIdx.x;
  const int swzb = (bid & 7) * (nwg >> 3) + (bid >> 3);   // all grids %8==0
  const int m0 = (swzb / gridDim.x) * 128, n0 = (swzb % gridDim.x) * 128;
  const int l16 = lane & 15, lq = lane >> 4;

  f32x4 acc[4][4];
#pragma unroll
  for (int i = 0; i < 4; ++i)
#pragma unroll
    for (int j = 0; j < 4; ++j) acc[i][j] = f32x4{0.f, 0.f, 0.f, 0.f};

  const int arow = tid >> 3;
  const int aslot = (tid & 7) ^ (arow & 7);
  const bf16* gA = A + (size_t)(m0 + arow) * lda + aslot * 8;
  const bf16* gB = BT + (size_t)(n0 + arow) * ldb + aslot * 8;
  const unsigned offw = (unsigned)__builtin_amdgcn_readfirstlane((tid & ~63) * 16);

  const int NT = K >> 6;
  auto stage = [&](int buf, int t) {
    char* p = lds + buf * 32768;
    const int k = t * 64;
#pragma unroll
    for (int it = 0; it < 4; ++it) {
      gld_lds16(gA + (size_t)it * 32 * lda + k, p + it * 4096 + offw);
      gld_lds16(gB + (size_t)it * 32 * ldb + k, p + 16384 + it * 4096 + offw);
    }
  };

  stage(0, 0);
  const unsigned swb = ((unsigned)(l16 & 7)) << 4;
  for (int t = 0; t < NT; ++t) {
    char* cur = lds + (t & 1) * 32768;
    if (t + 1 < NT) {
      stage((t + 1) & 1, t + 1);
      asm volatile("s_waitcnt vmcnt(8)" ::: "memory");
    } else {
      asm volatile("s_waitcnt vmcnt(0)" ::: "memory");
    }
    __builtin_amdgcn_s_barrier();
#pragma unroll
    for (int ks = 0; ks < 2; ++ks) {
      short8 af[4], bfr[4];
      const unsigned ko = ((unsigned)(ks * 64 + lq * 16)) ^ swb;
#pragma unroll
      for (int i = 0; i < 4; ++i) {
        af[i]  = *(const short8*)(cur + (wr * 64 + i * 16 + l16) * 128 + ko);
        bfr[i] = *(const short8*)(cur + 16384 + (wc * 64 + i * 16 + l16) * 128 + ko);
      }
#pragma unroll
      for (int i = 0; i < 4; ++i)
#pragma unroll
        for (int j = 0; j < 4; ++j)
          acc[i][j] = __builtin_amdgcn_mfma_f32_16x16x32_bf16(af[i], bfr[j], acc[i][j], 0, 0, 0);
    }
    __builtin_amdgcn_s_barrier();
  }

#pragma unroll
  for (int i = 0; i < 4; ++i) {
#pragma unroll
    for (int j = 0; j < 4; ++j) {
#pragma unroll
      for (int r = 0; r < 4; ++r) {
        int row = m0 + wr * 64 + i * 16 + lq * 4 + r;
        int col = n0 + wc * 64 + j * 16 + l16;
        float v = acc[i][j][r];
        if constexpr (EPI == 0) {
          int s = col / 768, d = col % 768;
          int b = row >> 8;
          const float* bs = (s == 0) ? p0 : (s == 1) ? p1 : p2;
          const float* ts = (s == 0) ? p3 : (s == 1) ? p4 : p5;
          v += bs[d] + ts[b * 768 + d];
          outB[(size_t)row * ldc + col] = __float2bfloat16(v);
        } else if constexpr (EPI == 1) {
          v += p0[col] + resid[(size_t)row * ldc + col];
          outF[(size_t)row * ldc + col] = v;
        } else if constexpr (EPI == 2) {
          v += p0[col];
          v = v / (1.f + __expf(-v));
          outB[(size_t)row * ldc + col] = __float2bfloat16(v);
        } else if constexpr (EPI == 3) {
          if (row < 32) {
            int l = col / 2304;
            int r2c = col - l * 2304;
            int s = r2c / 768, d = r2c - s * 768;
            const float* bs = (s == 0) ? p0 : (s == 1) ? p1 : p2;
            v += bs[l * 768 + d];
            outF[(size_t)((l * 3 + s) * 32 + row) * 768 + d] = v;
          }
        } else {
          if (col < 16) {
            v += p0[col];
            int b = row >> 8, n = row & 255;
            int gi = n >> 4, gj = n & 15;
            int c = col >> 2, pp = (col >> 1) & 1, qq = col & 1;
            outF[((b * 4 + c) * 32 + gi * 2 + pp) * 32 + gj * 2 + qq] = v;
          }
        }
      }
    }
  }
}

// ---------------- MFMA attention v3: transposed-S, single P buffer, setprio -------
// Grid remapped for XCD locality: all 12 heads of batch b dispatch at indices == b (mod 8),
// so they share one XCD's L2 for the b-slice of qkv. h = bid>>5, b = ((bid>>3)&3)*8+(bid&7).
__global__ __launch_bounds__(256) void attn_mfma(const bf16* __restrict__ qkv,
                                                 const bf16* __restrict__ btf,
                                                 bf16* __restrict__ obuf) {
  __shared__ __align__(16) char lds[49152];
  const int tid = threadIdx.x;
  const int wave = tid >> 6, lane = tid & 63;
  const int l16 = lane & 15, lq = lane >> 4;
  const int bid = blockIdx.x;
  const int h = bid >> 5;
  const int b = ((bid >> 3) & 3) * 8 + (bid & 7);
  const bf16* qb = qkv + (size_t)b * 256 * 2304;

  {
    const short8* vrow = (const short8*)(qb + (size_t)tid * 2304 + 1536 + h * 64);
    short8 vv[8];
#pragma unroll
    for (int c = 0; c < 8; ++c) vv[c] = vrow[c];
#pragma unroll
    for (int c = 0; c < 8; ++c)
#pragma unroll
      for (int e = 0; e < 8; ++e) {
        int d = c * 8 + e;
        unsigned off = (unsigned)(d * 512 + tid * 2) ^ ((unsigned)(d & 7) << 4);
        *(short*)(lds + off) = vv[c][e];
      }
  }
  short8 qf[4][2];
#pragma unroll
  for (int i = 0; i < 4; ++i)
#pragma unroll
    for (int ks = 0; ks < 2; ++ks)
      qf[i][ks] = *(const short8*)(qb + (size_t)(wave * 64 + i * 16 + l16) * 2304 +
                                   h * 64 + ks * 32 + lq * 8);
  __syncthreads();

  f32x4 oacc[4][4];
#pragma unroll
  for (int i = 0; i < 4; ++i)
#pragma unroll
    for (int j = 0; j < 4; ++j) oacc[i][j] = f32x4{0.f, 0.f, 0.f, 0.f};
  float lp[4] = {0.f, 0.f, 0.f, 0.f};
  const bf16* bl = btf + (size_t)h * 65536 + lane * 4;
  const unsigned swzv = ((unsigned)(l16 & 7)) << 4;
  const unsigned swzp = ((unsigned)(l16 & 3)) << 4;
  char* Pw = lds + 32768 + wave * 4096;

  for (int hc = 0; hc < 8; ++hc) {
    short8 kf[2][2];
#pragma unroll
    for (int jb = 0; jb < 2; ++jb) {
      const bf16* kr = qb + (size_t)(hc * 32 + jb * 16 + l16) * 2304 + 768 + h * 64 + lq * 8;
      kf[jb][0] = *(const short8*)(kr);
      kf[jb][1] = *(const short8*)(kr + 32);
    }
    f32x4 sacc[4][2];
#pragma unroll
    for (int i = 0; i < 4; ++i)
#pragma unroll
      for (int jb = 0; jb < 2; ++jb) {
        s16x4 bv = *(const s16x4*)(bl + ((size_t)((hc * 2 + jb) * 16 + wave * 4 + i) << 8));
        sacc[i][jb] = f32x4{b2f(bv[0]), b2f(bv[1]), b2f(bv[2]), b2f(bv[3])};
      }
    __builtin_amdgcn_s_setprio(1);
#pragma unroll
    for (int jb = 0; jb < 2; ++jb)
#pragma unroll
      for (int i = 0; i < 4; ++i) {
        sacc[i][jb] = __builtin_amdgcn_mfma_f32_16x16x32_bf16(kf[jb][0], qf[i][0], sacc[i][jb], 0, 0, 0);
        sacc[i][jb] = __builtin_amdgcn_mfma_f32_16x16x32_bf16(kf[jb][1], qf[i][1], sacc[i][jb], 0, 0, 0);
      }
    __builtin_amdgcn_s_setprio(0);
#pragma unroll
    for (int i = 0; i < 4; ++i)
#pragma unroll
      for (int jb = 0; jb < 2; ++jb) {
        float p0 = __expf(sacc[i][jb][0] * 0.125f);
        float p1 = __expf(sacc[i][jb][1] * 0.125f);
        float p2 = __expf(sacc[i][jb][2] * 0.125f);
        float p3 = __expf(sacc[i][jb][3] * 0.125f);
        lp[i] += (p0 + p1) + (p2 + p3);
        s16x4 pk = {f2bs(p0), f2bs(p1), f2bs(p2), f2bs(p3)};
        *(s16x4*)(Pw + (i * 16 + l16) * 64 + (((unsigned)(jb * 32 + lq * 8)) ^ swzp)) = pk;
      }
    asm volatile("s_waitcnt lgkmcnt(0)" ::: "memory");
    __builtin_amdgcn_sched_barrier(0);
    short8 pa[4], vb[4];
#pragma unroll
    for (int i = 0; i < 4; ++i)
      pa[i] = *(const short8*)(Pw + (i * 16 + l16) * 64 + (((unsigned)(lq * 16)) ^ swzp));
#pragma unroll
    for (int dj = 0; dj < 4; ++dj)
      vb[dj] = *(const short8*)(lds + (dj * 16 + l16) * 512 +
                                (((unsigned)(hc * 64 + lq * 16)) ^ swzv));
    __builtin_amdgcn_s_setprio(1);
#pragma unroll
    for (int i = 0; i < 4; ++i)
#pragma unroll
      for (int dj = 0; dj < 4; ++dj)
        oacc[i][dj] = __builtin_amdgcn_mfma_f32_16x16x32_bf16(pa[i], vb[dj], oacc[i][dj], 0, 0, 0);
    __builtin_amdgcn_s_setprio(0);
  }

#pragma unroll
  for (int i = 0; i < 4; ++i) {
    float l = lp[i];
    l += __shfl_xor(l, 16);
    l += __shfl_xor(l, 32);
#pragma unroll
    for (int r = 0; r < 4; ++r) {
      float linv = 1.f / __shfl(l, lq * 4 + r);
      int grow = b * 256 + wave * 64 + i * 16 + lq * 4 + r;
#pragma unroll
      for (int dj = 0; dj < 4; ++dj)
        obuf[(size_t)grow * 768 + h * 64 + dj * 16 + l16] =
            __float2bfloat16(oacc[i][dj][r] * linv);
    }
  }
}

extern "C" void kernel_launch(void* const* d_in, const int* in_sizes, int n_in,
                              void* d_out, int out_size, void* d_ws, size_t ws_size,
                              hipStream_t stream) {
  (void)in_sizes; (void)n_in; (void)out_size; (void)ws_size;
  const float* x       = (const float*)d_in[0];
  const float* t_in    = (const float*)d_in[1];
  const float* patch_w = (const float*)d_in[2];
  const float* patch_b = (const float*)d_in[3];
  const float* pos     = (const float*)d_in[4];
  const float* t_w1    = (const float*)d_in[5];
  const float* t_b1    = (const float*)d_in[6];
  const float* t_w2    = (const float*)d_in[7];
  const float* t_b2    = (const float*)d_in[8];
  const float* norm1_w = (const float*)d_in[9];
  const float* norm1_b = (const float*)d_in[10];
  const float* wqs     = (const float*)d_in[11];
  const float* bqs     = (const float*)d_in[12];
  const float* wqt     = (const float*)d_in[13];
  const float* bqt     = (const float*)d_in[14];
  const float* wks     = (const float*)d_in[15];
  const float* bks     = (const float*)d_in[16];
  const float* wkt     = (const float*)d_in[17];
  const float* bkt     = (const float*)d_in[18];
  const float* wvs     = (const float*)d_in[19];
  const float* bvs     = (const float*)d_in[20];
  const float* wvt     = (const float*)d_in[21];
  const float* bvt     = (const float*)d_in[22];
  const float* projw   = (const float*)d_in[23];
  const float* projb   = (const float*)d_in[24];
  const float* rpb     = (const float*)d_in[25];
  const float* norm2_w = (const float*)d_in[26];
  const float* norm2_b = (const float*)d_in[27];
  const float* mlp_w1  = (const float*)d_in[28];
  const float* mlp_b1  = (const float*)d_in[29];
  const float* mlp_w2  = (const float*)d_in[30];
  const float* mlp_b2  = (const float*)d_in[31];
  const float* norm_w  = (const float*)d_in[32];
  const float* norm_b  = (const float*)d_in[33];
  const float* dec_w   = (const float*)d_in[34];
  const float* dec_b   = (const float*)d_in[35];

  char* ws = (char*)d_ws;
  size_t off = 0;
  auto alloc = [&](size_t bytes) -> void* {
    void* p = ws + off;
    off += (bytes + 255) & ~(size_t)255;
    return p;
  };
  bf16* wqkvT = (bf16*)alloc(12ull * 2304 * 768 * 2);
  bf16* projT = (bf16*)alloc(12ull * 768 * 768 * 2);
  bf16* mlp1T = (bf16*)alloc(12ull * 3072 * 768 * 2);
  bf16* mlp2T = (bf16*)alloc(12ull * 768 * 3072 * 2);
  bf16* wtT   = (bf16*)alloc(12ull * 2304 * 768 * 2);
  float* xs   = (float*)alloc(8192ull * 768 * 4);
  bf16* hbuf  = (bf16*)alloc(8192ull * 768 * 2);
  bf16* qkvb  = (bf16*)alloc(8192ull * 2304 * 2);
  bf16* obuf  = (bf16*)alloc(8192ull * 768 * 2);
  bf16* btabf = (bf16*)alloc(12ull * 12 * 256 * 256 * 2);
  float* ttok = (float*)alloc(12ull * 3 * 32 * 768 * 4);
  bf16* xtb   = (bf16*)alloc(128ull * 768 * 2);
  bf16* dwT   = (bf16*)alloc(128ull * 768 * 2);
  float* emb  = (float*)alloc(32ull * 256 * 4);
  float* h1   = (float*)alloc(32ull * 768 * 4);
  bf16* hmlp  = qkvb;   // 8192*3072*2 fits in qkvb+obuf, both dead by mlp1

  hipMemsetAsync(xtb, 0, 128ull * 768 * 2, stream);
  hipMemsetAsync(dwT, 0, 128ull * 768 * 2, stream);

  transpose_conv3<<<dim3(24, 24, 36), 256, 0, stream>>>(wqs, wks, wvs, wqkvT, 2304ll * 768);
  transpose_conv3<<<dim3(24, 24, 36), 256, 0, stream>>>(wqt, wkt, wvt, wtT, 2304ll * 768);
  transpose_conv<<<dim3(24, 24, 12), 256, 0, stream>>>(projw, projT, 768, 768, 0, 768ll * 768);
  transpose_conv<<<dim3(96, 24, 12), 256, 0, stream>>>(mlp_w1, mlp1T, 768, 3072, 0, 3072ll * 768);
  transpose_conv<<<dim3(24, 96, 12), 256, 0, stream>>>(mlp_w2, mlp2T, 3072, 768, 0, 768ll * 3072);
  dec_transpose<<<48, 256, 0, stream>>>(dec_w, dwT);
  build_btab_frag<<<36864, 256, 0, stream>>>(rpb, btabf);

  temb_kernel<<<32, 128, 0, stream>>>(t_in, emb);
  smallmm_red<0><<<768, 256, 0, stream>>>(emb, t_w1, t_b1, h1, 256);
  smallmm_red<1><<<768, 256, 0, stream>>>(h1, t_w2, t_b2, xtb, 768);
  gemm128<3><<<dim3(216, 1), 256, 0, stream>>>(
      xtb, 768, wtT, 768, 768, bqt, bkt, bvt, nullptr, nullptr, nullptr,
      nullptr, ttok, nullptr, 0);

  patch_embed<<<8192, 256, 0, stream>>>(x, patch_w, patch_b, pos, xs);

  for (int l = 0; l < 12; ++l) {
    ln_bf16_kernel<<<2048, 256, 0, stream>>>(xs, norm1_w + l * 768, norm1_b + l * 768, hbuf);
    gemm128<0><<<dim3(18, 64), 256, 0, stream>>>(
        hbuf, 768, wqkvT + (size_t)l * 2304 * 768, 768, 768,
        bqs + l * 768, bks + l * 768, bvs + l * 768,
        ttok + (size_t)(l * 3 + 0) * 32 * 768,
        ttok + (size_t)(l * 3 + 1) * 32 * 768,
        ttok + (size_t)(l * 3 + 2) * 32 * 768,
        nullptr, nullptr, qkvb, 2304);
    attn_mfma<<<384, 256, 0, stream>>>(qkvb, btabf + (size_t)l * 12 * 65536, obuf);
    gemm128<1><<<dim3(6, 64), 256, 0, stream>>>(
        obuf, 768, projT + (size_t)l * 768 * 768, 768, 768,
        projb + l * 768, nullptr, nullptr, nullptr, nullptr, nullptr,
        xs, xs, nullptr, 768);
    ln_bf16_kernel<<<2048, 256, 0, stream>>>(xs, norm2_w + l * 768, norm2_b + l * 768, hbuf);
    gemm128<2><<<dim3(24, 64), 256, 0, stream>>>(
        hbuf, 768, mlp1T + (size_t)l * 3072 * 768, 768, 768,
        mlp_b1 + l * 3072, nullptr, nullptr, nullptr, nullptr, nullptr,
        nullptr, nullptr, hmlp, 3072);
    gemm128<1><<<dim3(6, 64), 256, 0, stream>>>(
        hmlp, 3072, mlp2T + (size_t)l * 768 * 3072, 3072, 3072,
        mlp_b2 + l * 768, nullptr, nullptr, nullptr, nullptr, nullptr,
        xs, xs, nullptr, 768);
  }
  ln_bf16_kernel<<<2048, 256, 0, stream>>>(xs, norm_w, norm_b, hbuf);
  gemm128<4><<<dim3(1, 64), 256, 0, stream>>>(
      hbuf, 768, dwT, 768, 768, dec_b, nullptr, nullptr, nullptr, nullptr, nullptr,
      nullptr, (float*)d_out, nullptr, 0);
}

// Round 15
// 2648.370 us; speedup vs baseline: 1.2391x; 1.0288x over previous
//
#include <hip/hip_runtime.h>
#include <hip/hip_bf16.h>

typedef __attribute__((ext_vector_type(8))) short short8;
typedef __attribute__((ext_vector_type(4))) short s16x4;
typedef __attribute__((ext_vector_type(4))) float f32x4;
typedef __hip_bfloat16 bf16;

#define AS1 __attribute__((address_space(1)))
#define AS3 __attribute__((address_space(3)))

__device__ __forceinline__ float b2f(short u) {
  union { unsigned int i; float f; } x;
  x.i = ((unsigned int)(unsigned short)u) << 16;
  return x.f;
}
__device__ __forceinline__ short f2bs(float f) {
  bf16 t = __float2bfloat16(f);
  return *reinterpret_cast<short*>(&t);
}

__device__ __forceinline__ void gld_lds16(const void* g, void* lds) {
  __builtin_amdgcn_global_load_lds((const AS1 unsigned int*)g,
                                   (AS3 unsigned int*)lds, 16, 0, 0);
}

// ---------------- weight transpose + fp32->bf16 convert ----------------
__global__ void transpose_conv(const float* __restrict__ src, bf16* __restrict__ dst,
                               int R, int C, int row_off, long long layer_stride) {
  __shared__ float t[32][33];
  int l = blockIdx.z;
  int r0 = blockIdx.y * 32;
  int c0 = blockIdx.x * 32;
  int tx = threadIdx.x & 31, ty = threadIdx.x >> 5;
  const float* s = src + (size_t)l * R * C;
#pragma unroll
  for (int i = 0; i < 4; ++i)
    t[ty + i * 8][tx] = s[(size_t)(r0 + ty + i * 8) * C + c0 + tx];
  __syncthreads();
  bf16* d = dst + (size_t)l * layer_stride;
#pragma unroll
  for (int i = 0; i < 4; ++i) {
    int n = c0 + ty + i * 8, k = r0 + tx;
    d[(size_t)(row_off + n) * R + k] = __float2bfloat16(t[tx][ty + i * 8]);
  }
}

// merged 3-source 768x768 transpose (qkv weight groups); z = l*3 + which
__global__ void transpose_conv3(const float* __restrict__ s0, const float* __restrict__ s1,
                                const float* __restrict__ s2, bf16* __restrict__ dst,
                                long long layer_stride) {
  __shared__ float t[32][33];
  int z = blockIdx.z;
  int which = z % 3, l = z / 3;
  const float* src = (which == 0) ? s0 : (which == 1) ? s1 : s2;
  int r0 = blockIdx.y * 32;
  int c0 = blockIdx.x * 32;
  int tx = threadIdx.x & 31, ty = threadIdx.x >> 5;
  const float* s = src + (size_t)l * 768 * 768;
#pragma unroll
  for (int i = 0; i < 4; ++i)
    t[ty + i * 8][tx] = s[(size_t)(r0 + ty + i * 8) * 768 + c0 + tx];
  __syncthreads();
  bf16* d = dst + (size_t)l * layer_stride;
#pragma unroll
  for (int i = 0; i < 4; ++i) {
    int n = c0 + ty + i * 8, k = r0 + tx;
    d[(size_t)(which * 768 + n) * 768 + k] = __float2bfloat16(t[tx][ty + i * 8]);
  }
}

// dec_w [768][16] fp32 -> dwT [j][k] bf16 (rows 16..127 pre-zeroed)
__global__ void dec_transpose(const float* __restrict__ dw, bf16* __restrict__ dwT) {
  int idx = blockIdx.x * 256 + threadIdx.x;   // 16*768
  if (idx >= 12288) return;
  int k = idx % 768, j = idx / 768;
  dwT[j * 768 + k] = __float2bfloat16(dw[k * 16 + j]);
}

// ---------------- patch embed + pos embed -> xs bf16 ----------------
__global__ __launch_bounds__(256) void patch_embed(const float* __restrict__ x,
                                                   const float* __restrict__ pw,
                                                   const float* __restrict__ pb,
                                                   const float* __restrict__ pos,
                                                   bf16* __restrict__ xs) {
  __shared__ float xp[16];
  int bn = blockIdx.x;             // [B][N]
  int n = bn & 255, b = bn >> 8;
  int gi = n >> 4, gj = n & 15;
  int tid = threadIdx.x;
  if (tid < 16) {
    int c = tid >> 2, p = (tid >> 1) & 1, q = tid & 1;
    xp[tid] = x[((b * 4 + c) * 32 + gi * 2 + p) * 32 + gj * 2 + q];
  }
  __syncthreads();
  float xv[16];
#pragma unroll
  for (int j = 0; j < 16; ++j) xv[j] = xp[j];
#pragma unroll
  for (int it = 0; it < 3; ++it) {
    int d = tid + it * 256;
    const float* pwr = pw + d * 16;
    float acc = pb[d];
#pragma unroll
    for (int j = 0; j < 16; ++j) acc += xv[j] * pwr[j];
    xs[(size_t)bn * 768 + d] = __float2bfloat16(acc + pos[n * 768 + d]);
  }
}

// ---------------- time embedding ----------------
__global__ void temb_kernel(const float* __restrict__ t, float* __restrict__ emb) {
  int b = blockIdx.x;
  int i = threadIdx.x;
  float f = __expf((float)i * (-logf(10000.f) / 127.f));
  float e = t[b] * f;
  emb[b * 256 + i] = sinf(e);
  emb[b * 256 + 128 + i] = cosf(e);
}

// small [32,K]@[K,768] with 8-way k-split + shuffle reduce. MODE 0: fp32+silu, 1: bf16
template <int MODE>
__global__ void smallmm_red(const float* __restrict__ in, const float* __restrict__ w,
                            const float* __restrict__ bias, void* __restrict__ out, int K) {
  int tid = threadIdx.x;
  int s = tid & 7, o = blockIdx.x * 32 + (tid >> 3);
  int d = o % 768, b = o / 768;
  int Ks = K >> 3, k0 = s * Ks;
  const float* ir = in + b * K + k0;
  const float* wr = w + (size_t)k0 * 768 + d;
  float a = 0.f;
  for (int i = 0; i < Ks; ++i) a += ir[i] * wr[(size_t)i * 768];
  a += __shfl_xor(a, 1);
  a += __shfl_xor(a, 2);
  a += __shfl_xor(a, 4);
  if (s == 0) {
    a += bias[d];
    if (MODE == 0) {
      a = a / (1.f + __expf(-a));
      ((float*)out)[o] = a;
    } else {
      ((bf16*)out)[o] = __float2bfloat16(a);
    }
  }
}

// bias table in MFMA D-fragment order, pre-scaled by 8
__global__ void build_btab_frag(const float* __restrict__ rpb, bf16* __restrict__ btf) {
  int idx = blockIdx.x * 256 + threadIdx.x;    // 12*12*65536
  int t = idx & 65535;
  int lh = idx >> 16;
  int h = lh % 12, l = lh / 12;
  int r = t & 3; t >>= 2;
  int lane = t & 63; t >>= 6;
  int i = t & 3; t >>= 2;
  int w = t & 3; t >>= 2;
  int jb = t & 1; t >>= 1;
  int hc = t & 7;
  int q = w * 64 + i * 16 + (lane & 15);
  int k = hc * 32 + jb * 16 + (lane >> 4) * 4 + r;
  int ih = (q >> 4) - (k >> 4) + 15;
  int iw = (q & 15) - (k & 15) + 15;
  btf[idx] = __float2bfloat16(8.0f * rpb[((l * 31 + ih) * 31 + iw) * 12 + h]);
}

// ---------------- LayerNorm bf16 -> bf16, wave-per-row (no LDS, no sync) ----------
__global__ __launch_bounds__(256) void ln_bf16_kernel(const bf16* __restrict__ x,
                                                      const float* __restrict__ w,
                                                      const float* __restrict__ b,
                                                      bf16* __restrict__ out) {
  int row = blockIdx.x * 4 + (threadIdx.x >> 6);
  int lane = threadIdx.x & 63;
  const bf16* xr = x + (size_t)row * 768;
  float v[12];
  float s = 0.f, s2 = 0.f;
#pragma unroll
  for (int k = 0; k < 12; ++k) {
    v[k] = __bfloat162float(xr[lane + k * 64]);
    s += v[k];
    s2 += v[k] * v[k];
  }
#pragma unroll
  for (int off = 32; off; off >>= 1) {
    s += __shfl_xor(s, off);
    s2 += __shfl_xor(s2, off);
  }
  float m = s * (1.f / 768.f);
  float var = s2 * (1.f / 768.f) - m * m;
  float r = rsqrtf(var + 1e-6f);
  bf16* orow = out + (size_t)row * 768;
#pragma unroll
  for (int k = 0; k < 12; ++k) {
    int c = lane + k * 64;
    orow[c] = __float2bfloat16((v[k] - m) * r * w[c] + b[c]);
  }
}

// ---------------- MFMA GEMM 128x128, BK=64, dbuf 2-phase, swizzled LDS ------------
// K-loop = R4 proven config (0 conflicts). Scalar epilogue (HW-coalesced stores).
// EPI 0: qkv bf16 (+bias+ttok, ldc=2304)
// EPI 1: bf16 out = acc + bias[col] + resid_bf16  (residual stream all-bf16)
// EPI 2: bf16 out = silu(acc + bias[col])
// EPI 3: ttok producer (rows<32);  4: decode/unpatchify (col<16, fp32 d_out)
template <int EPI>
__global__ __launch_bounds__(256) void gemm128(
    const bf16* __restrict__ A, int lda, const bf16* __restrict__ BT, int ldb, int K,
    const float* __restrict__ p0, const float* __restrict__ p1,
    const float* __restrict__ p2, const float* __restrict__ p3,
    const float* __restrict__ p4, const float* __restrict__ p5,
    const bf16* __restrict__ residB, float* __restrict__ outF,
    bf16* __restrict__ outB, int ldc) {
  __shared__ __align__(16) char lds[65536];
  const int tid = threadIdx.x;
  const int wid = tid >> 6, lane = tid & 63;
  const int wr = wid >> 1, wc = wid & 1;
  const int nwg = gridDim.x * gridDim.y;
  const int bid = blockIdx.y * gridDim.x + blockIdx.x;
  const int swzb = (bid & 7) * (nwg >> 3) + (bid >> 3);   // all grids %8==0
  const int m0 = (swzb / gridDim.x) * 128, n0 = (swzb % gridDim.x) * 128;
  const int l16 = lane & 15, lq = lane >> 4;

  f32x4 acc[4][4];
#pragma unroll
  for (int i = 0; i < 4; ++i)
#pragma unroll
    for (int j = 0; j < 4; ++j) acc[i][j] = f32x4{0.f, 0.f, 0.f, 0.f};

  const int arow = tid >> 3;
  const int aslot = (tid & 7) ^ (arow & 7);
  const bf16* gA = A + (size_t)(m0 + arow) * lda + aslot * 8;
  const bf16* gB = BT + (size_t)(n0 + arow) * ldb + aslot * 8;
  const unsigned offw = (unsigned)__builtin_amdgcn_readfirstlane((tid & ~63) * 16);

  const int NT = K >> 6;
  auto stage = [&](int buf, int t) {
    char* p = lds + buf * 32768;
    const int k = t * 64;
#pragma unroll
    for (int it = 0; it < 4; ++it) {
      gld_lds16(gA + (size_t)it * 32 * lda + k, p + it * 4096 + offw);
      gld_lds16(gB + (size_t)it * 32 * ldb + k, p + 16384 + it * 4096 + offw);
    }
  };

  stage(0, 0);
  const unsigned swb = ((unsigned)(l16 & 7)) << 4;
  for (int t = 0; t < NT; ++t) {
    char* cur = lds + (t & 1) * 32768;
    if (t + 1 < NT) {
      stage((t + 1) & 1, t + 1);
      asm volatile("s_waitcnt vmcnt(8)" ::: "memory");
    } else {
      asm volatile("s_waitcnt vmcnt(0)" ::: "memory");
    }
    __builtin_amdgcn_s_barrier();
#pragma unroll
    for (int ks = 0; ks < 2; ++ks) {
      short8 af[4], bfr[4];
      const unsigned ko = ((unsigned)(ks * 64 + lq * 16)) ^ swb;
#pragma unroll
      for (int i = 0; i < 4; ++i) {
        af[i]  = *(const short8*)(cur + (wr * 64 + i * 16 + l16) * 128 + ko);
        bfr[i] = *(const short8*)(cur + 16384 + (wc * 64 + i * 16 + l16) * 128 + ko);
      }
#pragma unroll
      for (int i = 0; i < 4; ++i)
#pragma unroll
        for (int j = 0; j < 4; ++j)
          acc[i][j] = __builtin_amdgcn_mfma_f32_16x16x32_bf16(af[i], bfr[j], acc[i][j], 0, 0, 0);
    }
    __builtin_amdgcn_s_barrier();
  }

#pragma unroll
  for (int i = 0; i < 4; ++i) {
#pragma unroll
    for (int j = 0; j < 4; ++j) {
#pragma unroll
      for (int r = 0; r < 4; ++r) {
        int row = m0 + wr * 64 + i * 16 + lq * 4 + r;
        int col = n0 + wc * 64 + j * 16 + l16;
        float v = acc[i][j][r];
        if constexpr (EPI == 0) {
          int s = col / 768, d = col % 768;
          int b = row >> 8;
          const float* bs = (s == 0) ? p0 : (s == 1) ? p1 : p2;
          const float* ts = (s == 0) ? p3 : (s == 1) ? p4 : p5;
          v += bs[d] + ts[b * 768 + d];
          outB[(size_t)row * ldc + col] = __float2bfloat16(v);
        } else if constexpr (EPI == 1) {
          v += p0[col] + __bfloat162float(residB[(size_t)row * ldc + col]);
          outB[(size_t)row * ldc + col] = __float2bfloat16(v);
        } else if constexpr (EPI == 2) {
          v += p0[col];
          v = v / (1.f + __expf(-v));
          outB[(size_t)row * ldc + col] = __float2bfloat16(v);
        } else if constexpr (EPI == 3) {
          if (row < 32) {
            int l = col / 2304;
            int r2c = col - l * 2304;
            int s = r2c / 768, d = r2c - s * 768;
            const float* bs = (s == 0) ? p0 : (s == 1) ? p1 : p2;
            v += bs[l * 768 + d];
            outF[(size_t)((l * 3 + s) * 32 + row) * 768 + d] = v;
          }
        } else {
          if (col < 16) {
            v += p0[col];
            int b = row >> 8, n = row & 255;
            int gi = n >> 4, gj = n & 15;
            int c = col >> 2, pp = (col >> 1) & 1, qq = col & 1;
            outF[((b * 4 + c) * 32 + gi * 2 + pp) * 32 + gj * 2 + qq] = v;
          }
        }
      }
    }
  }
}

// ---------------- MFMA attention v3: transposed-S, single P buffer, setprio -------
// Grid remapped for XCD locality: all 12 heads of batch b dispatch at indices == b (mod 8).
__global__ __launch_bounds__(256) void attn_mfma(const bf16* __restrict__ qkv,
                                                 const bf16* __restrict__ btf,
                                                 bf16* __restrict__ obuf) {
  __shared__ __align__(16) char lds[49152];
  const int tid = threadIdx.x;
  const int wave = tid >> 6, lane = tid & 63;
  const int l16 = lane & 15, lq = lane >> 4;
  const int bid = blockIdx.x;
  const int h = bid >> 5;
  const int b = ((bid >> 3) & 3) * 8 + (bid & 7);
  const bf16* qb = qkv + (size_t)b * 256 * 2304;

  {
    const short8* vrow = (const short8*)(qb + (size_t)tid * 2304 + 1536 + h * 64);
    short8 vv[8];
#pragma unroll
    for (int c = 0; c < 8; ++c) vv[c] = vrow[c];
#pragma unroll
    for (int c = 0; c < 8; ++c)
#pragma unroll
      for (int e = 0; e < 8; ++e) {
        int d = c * 8 + e;
        unsigned off = (unsigned)(d * 512 + tid * 2) ^ ((unsigned)(d & 7) << 4);
        *(short*)(lds + off) = vv[c][e];
      }
  }
  short8 qf[4][2];
#pragma unroll
  for (int i = 0; i < 4; ++i)
#pragma unroll
    for (int ks = 0; ks < 2; ++ks)
      qf[i][ks] = *(const short8*)(qb + (size_t)(wave * 64 + i * 16 + l16) * 2304 +
                                   h * 64 + ks * 32 + lq * 8);
  __syncthreads();

  f32x4 oacc[4][4];
#pragma unroll
  for (int i = 0; i < 4; ++i)
#pragma unroll
    for (int j = 0; j < 4; ++j) oacc[i][j] = f32x4{0.f, 0.f, 0.f, 0.f};
  float lp[4] = {0.f, 0.f, 0.f, 0.f};
  const bf16* bl = btf + (size_t)h * 65536 + lane * 4;
  const unsigned swzv = ((unsigned)(l16 & 7)) << 4;
  const unsigned swzp = ((unsigned)(l16 & 3)) << 4;
  char* Pw = lds + 32768 + wave * 4096;

  for (int hc = 0; hc < 8; ++hc) {
    short8 kf[2][2];
#pragma unroll
    for (int jb = 0; jb < 2; ++jb) {
      const bf16* kr = qb + (size_t)(hc * 32 + jb * 16 + l16) * 2304 + 768 + h * 64 + lq * 8;
      kf[jb][0] = *(const short8*)(kr);
      kf[jb][1] = *(const short8*)(kr + 32);
    }
    f32x4 sacc[4][2];
#pragma unroll
    for (int i = 0; i < 4; ++i)
#pragma unroll
      for (int jb = 0; jb < 2; ++jb) {
        s16x4 bv = *(const s16x4*)(bl + ((size_t)((hc * 2 + jb) * 16 + wave * 4 + i) << 8));
        sacc[i][jb] = f32x4{b2f(bv[0]), b2f(bv[1]), b2f(bv[2]), b2f(bv[3])};
      }
    __builtin_amdgcn_s_setprio(1);
#pragma unroll
    for (int jb = 0; jb < 2; ++jb)
#pragma unroll
      for (int i = 0; i < 4; ++i) {
        sacc[i][jb] = __builtin_amdgcn_mfma_f32_16x16x32_bf16(kf[jb][0], qf[i][0], sacc[i][jb], 0, 0, 0);
        sacc[i][jb] = __builtin_amdgcn_mfma_f32_16x16x32_bf16(kf[jb][1], qf[i][1], sacc[i][jb], 0, 0, 0);
      }
    __builtin_amdgcn_s_setprio(0);
#pragma unroll
    for (int i = 0; i < 4; ++i)
#pragma unroll
      for (int jb = 0; jb < 2; ++jb) {
        float p0 = __expf(sacc[i][jb][0] * 0.125f);
        float p1 = __expf(sacc[i][jb][1] * 0.125f);
        float p2 = __expf(sacc[i][jb][2] * 0.125f);
        float p3 = __expf(sacc[i][jb][3] * 0.125f);
        lp[i] += (p0 + p1) + (p2 + p3);
        s16x4 pk = {f2bs(p0), f2bs(p1), f2bs(p2), f2bs(p3)};
        *(s16x4*)(Pw + (i * 16 + l16) * 64 + (((unsigned)(jb * 32 + lq * 8)) ^ swzp)) = pk;
      }
    asm volatile("s_waitcnt lgkmcnt(0)" ::: "memory");
    __builtin_amdgcn_sched_barrier(0);
    short8 pa[4], vb[4];
#pragma unroll
    for (int i = 0; i < 4; ++i)
      pa[i] = *(const short8*)(Pw + (i * 16 + l16) * 64 + (((unsigned)(lq * 16)) ^ swzp));
#pragma unroll
    for (int dj = 0; dj < 4; ++dj)
      vb[dj] = *(const short8*)(lds + (dj * 16 + l16) * 512 +
                                (((unsigned)(hc * 64 + lq * 16)) ^ swzv));
    __builtin_amdgcn_s_setprio(1);
#pragma unroll
    for (int i = 0; i < 4; ++i)
#pragma unroll
      for (int dj = 0; dj < 4; ++dj)
        oacc[i][dj] = __builtin_amdgcn_mfma_f32_16x16x32_bf16(pa[i], vb[dj], oacc[i][dj], 0, 0, 0);
    __builtin_amdgcn_s_setprio(0);
  }

#pragma unroll
  for (int i = 0; i < 4; ++i) {
    float l = lp[i];
    l += __shfl_xor(l, 16);
    l += __shfl_xor(l, 32);
#pragma unroll
    for (int r = 0; r < 4; ++r) {
      float linv = 1.f / __shfl(l, lq * 4 + r);
      int grow = b * 256 + wave * 64 + i * 16 + lq * 4 + r;
#pragma unroll
      for (int dj = 0; dj < 4; ++dj)
        obuf[(size_t)grow * 768 + h * 64 + dj * 16 + l16] =
            __float2bfloat16(oacc[i][dj][r] * linv);
    }
  }
}

extern "C" void kernel_launch(void* const* d_in, const int* in_sizes, int n_in,
                              void* d_out, int out_size, void* d_ws, size_t ws_size,
                              hipStream_t stream) {
  (void)in_sizes; (void)n_in; (void)out_size; (void)ws_size;
  const float* x       = (const float*)d_in[0];
  const float* t_in    = (const float*)d_in[1];
  const float* patch_w = (const float*)d_in[2];
  const float* patch_b = (const float*)d_in[3];
  const float* pos     = (const float*)d_in[4];
  const float* t_w1    = (const float*)d_in[5];
  const float* t_b1    = (const float*)d_in[6];
  const float* t_w2    = (const float*)d_in[7];
  const float* t_b2    = (const float*)d_in[8];
  const float* norm1_w = (const float*)d_in[9];
  const float* norm1_b = (const float*)d_in[10];
  const float* wqs     = (const float*)d_in[11];
  const float* bqs     = (const float*)d_in[12];
  const float* wqt     = (const float*)d_in[13];
  const float* bqt     = (const float*)d_in[14];
  const float* wks     = (const float*)d_in[15];
  const float* bks     = (const float*)d_in[16];
  const float* wkt     = (const float*)d_in[17];
  const float* bkt     = (const float*)d_in[18];
  const float* wvs     = (const float*)d_in[19];
  const float* bvs     = (const float*)d_in[20];
  const float* wvt     = (const float*)d_in[21];
  const float* bvt     = (const float*)d_in[22];
  const float* projw   = (const float*)d_in[23];
  const float* projb   = (const float*)d_in[24];
  const float* rpb     = (const float*)d_in[25];
  const float* norm2_w = (const float*)d_in[26];
  const float* norm2_b = (const float*)d_in[27];
  const float* mlp_w1  = (const float*)d_in[28];
  const float* mlp_b1  = (const float*)d_in[29];
  const float* mlp_w2  = (const float*)d_in[30];
  const float* mlp_b2  = (const float*)d_in[31];
  const float* norm_w  = (const float*)d_in[32];
  const float* norm_b  = (const float*)d_in[33];
  const float* dec_w   = (const float*)d_in[34];
  const float* dec_b   = (const float*)d_in[35];

  char* ws = (char*)d_ws;
  size_t off = 0;
  auto alloc = [&](size_t bytes) -> void* {
    void* p = ws + off;
    off += (bytes + 255) & ~(size_t)255;
    return p;
  };
  bf16* wqkvT = (bf16*)alloc(12ull * 2304 * 768 * 2);
  bf16* projT = (bf16*)alloc(12ull * 768 * 768 * 2);
  bf16* mlp1T = (bf16*)alloc(12ull * 3072 * 768 * 2);
  bf16* mlp2T = (bf16*)alloc(12ull * 768 * 3072 * 2);
  bf16* wtT   = (bf16*)alloc(12ull * 2304 * 768 * 2);
  bf16* xs    = (bf16*)alloc(8192ull * 768 * 2);       // residual stream, bf16
  bf16* hbuf  = (bf16*)alloc(8192ull * 768 * 2);
  bf16* qkvb  = (bf16*)alloc(8192ull * 2304 * 2);
  bf16* obuf  = (bf16*)alloc(8192ull * 768 * 2);
  bf16* btabf = (bf16*)alloc(12ull * 12 * 256 * 256 * 2);
  float* ttok = (float*)alloc(12ull * 3 * 32 * 768 * 4);
  bf16* xtb   = (bf16*)alloc(128ull * 768 * 2);
  bf16* dwT   = (bf16*)alloc(128ull * 768 * 2);
  float* emb  = (float*)alloc(32ull * 256 * 4);
  float* h1   = (float*)alloc(32ull * 768 * 4);
  bf16* hmlp  = qkvb;   // 8192*3072*2 fits in qkvb+obuf, both dead by mlp1

  hipMemsetAsync(xtb, 0, 128ull * 768 * 2, stream);
  hipMemsetAsync(dwT, 0, 128ull * 768 * 2, stream);

  transpose_conv3<<<dim3(24, 24, 36), 256, 0, stream>>>(wqs, wks, wvs, wqkvT, 2304ll * 768);
  transpose_conv3<<<dim3(24, 24, 36), 256, 0, stream>>>(wqt, wkt, wvt, wtT, 2304ll * 768);
  transpose_conv<<<dim3(24, 24, 12), 256, 0, stream>>>(projw, projT, 768, 768, 0, 768ll * 768);
  transpose_conv<<<dim3(96, 24, 12), 256, 0, stream>>>(mlp_w1, mlp1T, 768, 3072, 0, 3072ll * 768);
  transpose_conv<<<dim3(24, 96, 12), 256, 0, stream>>>(mlp_w2, mlp2T, 3072, 768, 0, 768ll * 3072);
  dec_transpose<<<48, 256, 0, stream>>>(dec_w, dwT);
  build_btab_frag<<<36864, 256, 0, stream>>>(rpb, btabf);

  temb_kernel<<<32, 128, 0, stream>>>(t_in, emb);
  smallmm_red<0><<<768, 256, 0, stream>>>(emb, t_w1, t_b1, h1, 256);
  smallmm_red<1><<<768, 256, 0, stream>>>(h1, t_w2, t_b2, xtb, 768);
  gemm128<3><<<dim3(216, 1), 256, 0, stream>>>(
      xtb, 768, wtT, 768, 768, bqt, bkt, bvt, nullptr, nullptr, nullptr,
      nullptr, ttok, nullptr, 0);

  patch_embed<<<8192, 256, 0, stream>>>(x, patch_w, patch_b, pos, xs);

  for (int l = 0; l < 12; ++l) {
    ln_bf16_kernel<<<2048, 256, 0, stream>>>(xs, norm1_w + l * 768, norm1_b + l * 768, hbuf);
    gemm128<0><<<dim3(18, 64), 256, 0, stream>>>(
        hbuf, 768, wqkvT + (size_t)l * 2304 * 768, 768, 768,
        bqs + l * 768, bks + l * 768, bvs + l * 768,
        ttok + (size_t)(l * 3 + 0) * 32 * 768,
        ttok + (size_t)(l * 3 + 1) * 32 * 768,
        ttok + (size_t)(l * 3 + 2) * 32 * 768,
        nullptr, nullptr, qkvb, 2304);
    attn_mfma<<<384, 256, 0, stream>>>(qkvb, btabf + (size_t)l * 12 * 65536, obuf);
    gemm128<1><<<dim3(6, 64), 256, 0, stream>>>(
        obuf, 768, projT + (size_t)l * 768 * 768, 768, 768,
        projb + l * 768, nullptr, nullptr, nullptr, nullptr, nullptr,
        xs, nullptr, xs, 768);
    ln_bf16_kernel<<<2048, 256, 0, stream>>>(xs, norm2_w + l * 768, norm2_b + l * 768, hbuf);
    gemm128<2><<<dim3(24, 64), 256, 0, stream>>>(
        hbuf, 768, mlp1T + (size_t)l * 3072 * 768, 768, 768,
        mlp_b1 + l * 3072, nullptr, nullptr, nullptr, nullptr, nullptr,
        nullptr, nullptr, hmlp, 3072);
    gemm128<1><<<dim3(6, 64), 256, 0, stream>>>(
        hmlp, 3072, mlp2T + (size_t)l * 768 * 3072, 3072, 3072,
        mlp_b2 + l * 768, nullptr, nullptr, nullptr, nullptr, nullptr,
        xs, nullptr, xs, 768);
  }
  ln_bf16_kernel<<<2048, 256, 0, stream>>>(xs, norm_w, norm_b, hbuf);
  gemm128<4><<<dim3(1, 64), 256, 0, stream>>>(
      hbuf, 768, dwT, 768, 768, dec_b, nullptr, nullptr, nullptr, nullptr, nullptr,
      nullptr, (float*)d_out, nullptr, 0);
}